// Round 5
// baseline (718.591 us; speedup 1.0000x reference)
//
#include <hip/hip_runtime.h>
#include <cstdint>
#include <climits>

static constexpr int DM   = 128;
static constexpr int NCOL = 96;
static constexpr int NATT = 32;
static constexpr int VOXC = 8;
static constexpr int CAP  = 32768;
static constexpr int GRID = 512;   // co-residency: LDS 24KB->6/CU, LB(256,4)->128 VGPR->4/CU, need 2/CU
static constexpr int BLK  = 256;
static constexpr float MARGIN = 4.0f;

// ws layout (ints). Poison 0xAAAAAAAA is negative as int -> barrier compares are safe.
static constexpr int OFF_FLAGS = 8;      // [512] per-block barrier flags
static constexpr int OFF_READY = 520;    // [1] barrier broadcast word
static constexpr int OFF_MM    = 528;    // [512*6] per-block minmax partials
static constexpr int OFF_B     = 3600;   // [6144] B fragments (24 KB)
static constexpr int OFF_BP    = 9744;   // [96] permuted b_off
static constexpr int OFF_CAND  = 9840;   // [CAP] candidate pt ids
static constexpr int OFF_FINAL = 42608;  // [CAP] confirmed pt ids
static constexpr int OFF_BITS  = 75376;  // [n] exact 32-bit masks

typedef __attribute__((ext_vector_type(8))) short bf16x8;
typedef __attribute__((ext_vector_type(4))) float f32x4;

__device__ inline unsigned f2bf_rne(float f) {
  unsigned u = __float_as_uint(f);
  return (u + 0x7fffu + ((u >> 16) & 1u)) >> 16;
}
// dim j = u>>1 of triple t=(u&1)*16+nn -> orig col t*3+j (in-lane triple-AND layout)
__device__ inline int colperm(int u, int nn) {
  return ((u & 1) * 16 + nn) * 3 + (u >> 1);
}

// Poison-tolerant grid barrier: every block WRITES flags[bid]=round (so stale/poison
// never satisfies the wait), block 0 scans then broadcasts via ready. Device-scope
// atomics + threadfence handle cross-XCD visibility (G16).
__device__ inline void gridbar(int* flags, int* ready, int round) {
  __syncthreads();
  __threadfence();
  if (threadIdx.x == 0)
    __hip_atomic_store(&flags[blockIdx.x], round, __ATOMIC_RELEASE, __HIP_MEMORY_SCOPE_AGENT);
  if (blockIdx.x == 0) {
    for (int j = threadIdx.x; j < GRID; j += BLK)
      while (__hip_atomic_load(&flags[j], __ATOMIC_ACQUIRE, __HIP_MEMORY_SCOPE_AGENT) < round) {}
    __syncthreads();
    if (threadIdx.x == 0)
      __hip_atomic_store(ready, round, __ATOMIC_RELEASE, __HIP_MEMORY_SCOPE_AGENT);
  }
  if (threadIdx.x == 0)
    while (__hip_atomic_load(ready, __ATOMIC_ACQUIRE, __HIP_MEMORY_SCOPE_AGENT) < round) {}
  __threadfence();
  __syncthreads();
}

__global__ __launch_bounds__(BLK, 4) void k_fused(
    const float* __restrict__ q, const float* __restrict__ vfea,
    const int* __restrict__ coords,
    const float* __restrict__ Woff, const float* __restrict__ boff,
    const float* __restrict__ Wattn, const float* __restrict__ battn,
    const float* __restrict__ Wval, const float* __restrict__ bval,
    const float* __restrict__ Wout, const float* __restrict__ bout,
    float* __restrict__ out, int n, int* __restrict__ ws) {
  __shared__ int4 bfr[24 * 64];  // 24 KB B fragments
  __shared__ int smn[3], smx[3];

  const int t = threadIdx.x, bid = blockIdx.x;
  const int wave = t >> 6, lane = t & 63;
  int* flags = ws + OFF_FLAGS;
  int* ready = ws + OFF_READY;

  // ---------- phase 1: counters, B-frag prep (block 0), coords minmax partials ----------
  if (t < 3) { smn[t] = INT_MAX; smx[t] = INT_MIN; }
  if (bid == 0 && t < 2) ws[6 + t] = 0;  // cand / final counters
  __syncthreads();

  if (bid == 0) {
    for (int idx = t; idx < 24 * 64; idx += BLK) {
      int f = idx >> 6, l = idx & 63;
      int s = f / 6, u = f - 6 * s;
      int col = colperm(u, l & 15);
      int k0 = s * 32 + (l >> 4) * 8;
      int4 d;
      d.x = (int)((f2bf_rne(Woff[(k0 + 1) * NCOL + col]) << 16) | f2bf_rne(Woff[(k0 + 0) * NCOL + col]));
      d.y = (int)((f2bf_rne(Woff[(k0 + 3) * NCOL + col]) << 16) | f2bf_rne(Woff[(k0 + 2) * NCOL + col]));
      d.z = (int)((f2bf_rne(Woff[(k0 + 5) * NCOL + col]) << 16) | f2bf_rne(Woff[(k0 + 4) * NCOL + col]));
      d.w = (int)((f2bf_rne(Woff[(k0 + 7) * NCOL + col]) << 16) | f2bf_rne(Woff[(k0 + 6) * NCOL + col]));
      reinterpret_cast<int4*>(ws + OFF_B)[idx] = d;
    }
    for (int j = t; j < 96; j += BLK)
      reinterpret_cast<float*>(ws + OFF_BP)[j] = boff[colperm(j >> 4, j & 15)];
  }

  {
    int mn[3] = {INT_MAX, INT_MAX, INT_MAX};
    int mx[3] = {INT_MIN, INT_MIN, INT_MIN};
    for (int i = bid * BLK + t; i < n; i += GRID * BLK) {
#pragma unroll
      for (int d = 0; d < 3; ++d) {
        int v = coords[i * 3 + d];
        mn[d] = min(mn[d], v);
        mx[d] = max(mx[d], v);
      }
    }
#pragma unroll
    for (int d = 0; d < 3; ++d)
      for (int off = 32; off > 0; off >>= 1) {
        mn[d] = min(mn[d], __shfl_xor(mn[d], off, 64));
        mx[d] = max(mx[d], __shfl_xor(mx[d], off, 64));
      }
    if (lane == 0) {
#pragma unroll
      for (int d = 0; d < 3; ++d) {
        atomicMin(&smn[d], mn[d]);
        atomicMax(&smx[d], mx[d]);
      }
    }
    __syncthreads();
    if (t < 3) {
      ws[OFF_MM + bid * 6 + t]     = smn[t];
      ws[OFF_MM + bid * 6 + 3 + t] = smx[t];
    }
  }

  gridbar(flags, ready, 1);

  // ---------- stage B frags to LDS; reduce global minmax (every block) ----------
  for (int idx = t; idx < 24 * 64; idx += BLK)
    bfr[idx] = reinterpret_cast<const int4*>(ws + OFF_B)[idx];
  if (t < 3) { smn[t] = INT_MAX; smx[t] = INT_MIN; }
  __syncthreads();
  for (int j = t; j < GRID; j += BLK) {
#pragma unroll
    for (int d = 0; d < 3; ++d) {
      atomicMin(&smn[d], ws[OFF_MM + j * 6 + d]);
      atomicMax(&smx[d], ws[OFF_MM + j * 6 + 3 + d]);
    }
  }
  __syncthreads();
  const int mn0 = smn[0], mn1 = smn[1], mn2 = smn[2];
  const int mx0 = smx[0], mx1 = smx[1], mx2 = smx[2];
  const float rc0 = (float)(mx0 - mn0), rc1 = (float)(mx1 - mn1), rc2 = (float)(mx2 - mn2);

  // ---------- phase 2: MFMA screen over tiles (sync-free, grid-stride) ----------
  {
    const float rcs[3] = {rc0 * 0.5f, rc1 * 0.5f, rc2 * 0.5f};
    const float* bp = reinterpret_cast<const float*>(ws + OFF_BP);
    const int m = lane & 15, quad = lane >> 4;
    float binit[6];
#pragma unroll
    for (int u = 0; u < 6; ++u) binit[u] = bp[u * 16 + m];
    const float4 bv4 = reinterpret_cast<const float4*>(bout)[lane & 31];
    const int ntiles = (n + 63) >> 6;

    for (int tile = bid; tile < ntiles; tile += GRID) {
      const int base = tile * 64 + wave * 16;
      // prefill out rows with b_out (col = lane&31 is lane-constant -> coalesced)
#pragma unroll
      for (int i = 0; i < 8; ++i) {
        int idx = lane + 64 * i;
        int row = base + (idx >> 5);
        if (row < n)
          reinterpret_cast<float4*>(out)[(size_t)row * 32 + (idx & 31)] = bv4;
      }
      const int prow = base + m;
      const float4* qr = reinterpret_cast<const float4*>(q + (size_t)min(prow, n - 1) * DM);
      f32x4 acc[6];
#pragma unroll
      for (int u = 0; u < 6; ++u) acc[u] = (f32x4){binit[u], binit[u], binit[u], binit[u]};
#pragma unroll
      for (int s = 0; s < 4; ++s) {
        float4 x = qr[s * 8 + quad * 2];
        float4 y = qr[s * 8 + quad * 2 + 1];
        union { int4 i; bf16x8 h; } A;  // truncation pack; MARGIN covers it
        A.i.x = (int)((__float_as_uint(x.y) & 0xffff0000u) | (__float_as_uint(x.x) >> 16));
        A.i.y = (int)((__float_as_uint(x.w) & 0xffff0000u) | (__float_as_uint(x.z) >> 16));
        A.i.z = (int)((__float_as_uint(y.y) & 0xffff0000u) | (__float_as_uint(y.x) >> 16));
        A.i.w = (int)((__float_as_uint(y.w) & 0xffff0000u) | (__float_as_uint(y.z) >> 16));
#pragma unroll
        for (int u = 0; u < 6; ++u) {
          union { int4 i; bf16x8 h; } B;
          B.i = bfr[(s * 6 + u) * 64 + lane];
          acc[u] = __builtin_amdgcn_mfma_f32_16x16x32_bf16(A.h, B.h, acc[u], 0, 0, 0);
        }
      }
      unsigned long long b[4];
#pragma unroll
      for (int r = 0; r < 4; ++r) {
        bool any = false;
#pragma unroll
        for (int g = 0; g < 2; ++g) {
          bool ok = true;
#pragma unroll
          for (int j = 0; j < 3; ++j) {
            float off = acc[2 * j + g][r] * rcs[j];
            ok = ok && (off > -1.0f - MARGIN) && (off < 8.0f + MARGIN);
          }
          any = any || ok;
        }
        b[r] = __ballot(any);
      }
      if (lane < 16) {
        int point = base + lane;
        unsigned long long bb = (lane & 1) ? ((lane & 2) ? b[3] : b[1])
                                           : ((lane & 2) ? b[2] : b[0]);
        if (point < n && ((bb >> ((lane >> 2) * 16)) & 0xffffull)) {
          int pos = atomicAdd(&ws[6], 1);
          if (pos < CAP) ws[OFF_CAND + pos] = point;
        }
      }
    }
  }

  gridbar(flags, ready, 2);

  // ---------- phase 3: exact fp32 recheck (per-wave, sync-free ballot) ----------
  {
    const int C = min(__hip_atomic_load(&ws[6], __ATOMIC_RELAXED, __HIP_MEMORY_SCOPE_AGENT), CAP);
    int* bits = ws + OFF_BITS;
    const int c0 = lane, c1 = 64 + (lane & 31);
    const int d0 = c0 % 3, d1 = c1 % 3;
    const float s0h = 0.5f * (d0 == 0 ? rc0 : (d0 == 1 ? rc1 : rc2));
    const float s1h = 0.5f * (d1 == 0 ? rc0 : (d1 == 1 ? rc1 : rc2));
    for (int i = bid * 4 + wave; i < C; i += GRID * 4) {
      int pt = ws[OFF_CAND + i];
      const float* qrow = q + (size_t)pt * DM;
      float a0 = boff[c0], a1 = boff[c1];
      for (int k = 0; k < DM; ++k) {
        float qk = qrow[k];
        a0 = fmaf(qk, Woff[k * NCOL + c0], a0);
        a1 = fmaf(qk, Woff[k * NCOL + c1], a1);
      }
      int o0 = (int)(a0 * s0h), o1 = (int)(a1 * s1h);
      unsigned long long m0 = __ballot(o0 >= 0 && o0 < VOXC);  // bit l = col l
      unsigned long long m1 = __ballot(o1 >= 0 && o1 < VOXC);  // bit l(&31) = col 64+l
      bool mt = false;
      if (lane < 32) {
        int cA = 3 * lane;
        bool bA = (cA < 64) ? ((m0 >> cA) & 1) : ((m1 >> (cA - 64)) & 1);
        bool bB = (cA + 1 < 64) ? ((m0 >> (cA + 1)) & 1) : ((m1 >> (cA - 63)) & 1);
        bool bC = (cA + 2 < 64) ? ((m0 >> (cA + 2)) & 1) : ((m1 >> (cA - 62)) & 1);
        mt = bA && bB && bC;
      }
      unsigned bits32 = (unsigned)__ballot(mt);
      if (lane == 0 && bits32) {
        bits[pt] = (int)bits32;
        int pos = atomicAdd(&ws[7], 1);
        if (pos < CAP) ws[OFF_FINAL + pos] = pt;
      }
    }
  }

  gridbar(flags, ready, 3);

  // ---------- phase 4: active points (per-wave, sync-free) ----------
  {
    const int count = min(__hip_atomic_load(&ws[7], __ATOMIC_RELAXED, __HIP_MEMORY_SCOPE_AGENT), CAP);
    const float rv0 = (float)((mx0 - mn0) / VOXC + 1);
    const float rv1 = (float)((mx1 - mn1) / VOXC + 1);
    const int* bits_arr = ws + OFF_BITS;

    for (int i = bid * 4 + wave; i < count; i += GRID * 4) {
      int pt = ws[OFF_FINAL + i];
      unsigned int bits = (unsigned int)bits_arr[pt];

      float i0 = (float)(coords[pt * 3 + 0] - mn0) * 0.125f;
      float i1 = (float)(coords[pt * 3 + 1] - mn1) * 0.125f;
      float i2 = (float)(coords[pt * 3 + 2] - mn2) * 0.125f;
      float flat = i0 * rv1 * rv0 + i1 * rv0 + i2;
      int g = (int)floorf(flat);
      g = min(max(g, 0), n - 1);

      const float* qrow = q + (size_t)pt * DM;

      float w_h = 0.0f;
      if (lane < NATT) {
        float acc = battn[lane];
        for (int k = 0; k < DM; ++k) acc = fmaf(qrow[k], Wattn[k * NATT + lane], acc);
        float mxv = acc;
        mxv = fmaxf(mxv, __shfl_xor(mxv, 1, 4));
        mxv = fmaxf(mxv, __shfl_xor(mxv, 2, 4));
        float e = expf(acc - mxv);
        float s = e;
        s += __shfl_xor(s, 1, 4);
        s += __shfl_xor(s, 2, 4);
        float a = e / s;
        float am = ((bits >> lane) & 1u) ? a : 0.0f;
        float w = am;
        w += __shfl_xor(w, 1, 4);
        w += __shfl_xor(w, 2, 4);
        w_h = w;
      }

      const float* vrow = vfea + (size_t)g * DM;
      float v0 = bval[lane], v1 = bval[lane + 64];
      for (int k = 0; k < DM; ++k) {
        float f = vrow[k];
        v0 = fmaf(f, Wval[k * DM + lane], v0);
        v1 = fmaf(f, Wval[k * DM + lane + 64], v1);
      }
      float wh0 = __shfl(w_h, (lane >> 4) * 4, 64);
      float wh1 = __shfl(w_h, ((lane >> 4) + 4) * 4, 64);
      float o0 = wh0 * v0;
      float o1 = wh1 * v1;

      float s0 = 0.0f, s1 = 0.0f;
      for (int d = 0; d < 64; ++d) {
        float od = __shfl(o0, d, 64);
        s0 = fmaf(od, Wout[d * DM + lane], s0);
        s1 = fmaf(od, Wout[d * DM + lane + 64], s1);
      }
      for (int d = 0; d < 64; ++d) {
        float od = __shfl(o1, d, 64);
        s0 = fmaf(od, Wout[(d + 64) * DM + lane], s0);
        s1 = fmaf(od, Wout[(d + 64) * DM + lane + 64], s1);
      }
      out[(size_t)pt * DM + lane] += s0;
      out[(size_t)pt * DM + lane + 64] += s1;
    }
  }
}

extern "C" void kernel_launch(void* const* d_in, const int* in_sizes, int n_in,
                              void* d_out, int out_size, void* d_ws, size_t ws_size,
                              hipStream_t stream) {
  const float* q     = (const float*)d_in[0];
  const float* vfea  = (const float*)d_in[1];
  const int*   coords= (const int*)d_in[2];
  const float* Woff  = (const float*)d_in[3];
  const float* boff  = (const float*)d_in[4];
  const float* Wattn = (const float*)d_in[5];
  const float* battn = (const float*)d_in[6];
  const float* Wval  = (const float*)d_in[7];
  const float* bval  = (const float*)d_in[8];
  const float* Wout  = (const float*)d_in[9];
  const float* bout  = (const float*)d_in[10];
  float* out = (float*)d_out;
  int n = in_sizes[0] / DM;
  int* ws = (int*)d_ws;

  k_fused<<<GRID, BLK, 0, stream>>>(q, vfea, coords, Woff, boff, Wattn, battn,
                                    Wval, bval, Wout, bout, out, n, ws);
}

// Round 6
// 466.538 us; speedup vs baseline: 1.5403x; 1.5403x over previous
//
#include <hip/hip_runtime.h>
#include <cstdint>
#include <climits>

static constexpr int DM   = 128;
static constexpr int NCOL = 96;
static constexpr int NATT = 32;
static constexpr int VOXC = 8;
static constexpr int PREP_GRID = 64;
static constexpr int MAIN_GRID = 768;   // 3 blocks/CU (LB(256,3) -> <=170 VGPR; LDS 24.6KB -> 6/CU)
static constexpr float MARGIN = 4.0f;

// ws layout (ints) — everything is write-then-read across the 2 dispatches; no init needed.
static constexpr int OFF_MM = 8;             // [64*6] per-block minmax partials
static constexpr int OFF_B  = 392;           // [6144] B fragments (byte 1568, 16B aligned)
static constexpr int OFF_BP = 392 + 6144;    // [96] permuted b_off

typedef __attribute__((ext_vector_type(8))) short bf16x8;
typedef __attribute__((ext_vector_type(4))) float f32x4;

__device__ inline unsigned f2bf_rne(float f) {
  unsigned u = __float_as_uint(f);
  return (u + 0x7fffu + ((u >> 16) & 1u)) >> 16;
}
// dim j = u>>1 of triple t=(u&1)*16+nn -> orig col t*3+j (in-lane triple-AND layout)
__device__ inline int colperm(int u, int nn) {
  return ((u & 1) * 16 + nn) * 3 + (u >> 1);
}

// minmax partials + B-frag bf16 conversion + permuted b_off
__global__ __launch_bounds__(256) void k_prep(const int* __restrict__ coords,
                                              const float* __restrict__ Woff,
                                              const float* __restrict__ boff,
                                              int n, int* __restrict__ ws) {
  const int t = threadIdx.x, bid = blockIdx.x;
  __shared__ int smn[3], smx[3];

  int idx = bid * 256 + t;
  if (idx < 24 * 64) {
    int f = idx >> 6, l = idx & 63;
    int s = f / 6, u = f - 6 * s;
    int col = colperm(u, l & 15);
    int k0 = s * 32 + (l >> 4) * 8;
    int4 d;
    d.x = (int)((f2bf_rne(Woff[(k0 + 1) * NCOL + col]) << 16) | f2bf_rne(Woff[(k0 + 0) * NCOL + col]));
    d.y = (int)((f2bf_rne(Woff[(k0 + 3) * NCOL + col]) << 16) | f2bf_rne(Woff[(k0 + 2) * NCOL + col]));
    d.z = (int)((f2bf_rne(Woff[(k0 + 5) * NCOL + col]) << 16) | f2bf_rne(Woff[(k0 + 4) * NCOL + col]));
    d.w = (int)((f2bf_rne(Woff[(k0 + 7) * NCOL + col]) << 16) | f2bf_rne(Woff[(k0 + 6) * NCOL + col]));
    reinterpret_cast<int4*>(ws + OFF_B)[idx] = d;
  }
  if (bid == 6 && t < 96)
    reinterpret_cast<float*>(ws + OFF_BP)[t] = boff[colperm(t >> 4, t & 15)];

  if (t < 3) { smn[t] = INT_MAX; smx[t] = INT_MIN; }
  __syncthreads();
  int mn[3] = {INT_MAX, INT_MAX, INT_MAX};
  int mx[3] = {INT_MIN, INT_MIN, INT_MIN};
  for (int i = bid * 256 + t; i < n; i += PREP_GRID * 256) {
#pragma unroll
    for (int d = 0; d < 3; ++d) {
      int v = coords[i * 3 + d];
      mn[d] = min(mn[d], v);
      mx[d] = max(mx[d], v);
    }
  }
#pragma unroll
  for (int d = 0; d < 3; ++d)
    for (int off = 32; off > 0; off >>= 1) {
      mn[d] = min(mn[d], __shfl_xor(mn[d], off, 64));
      mx[d] = max(mx[d], __shfl_xor(mx[d], off, 64));
    }
  if ((t & 63) == 0) {
#pragma unroll
    for (int d = 0; d < 3; ++d) {
      atomicMin(&smn[d], mn[d]);
      atomicMax(&smx[d], mx[d]);
    }
  }
  __syncthreads();
  if (t < 3) {
    ws[OFF_MM + bid * 6 + t]     = smn[t];
    ws[OFF_MM + bid * 6 + 3 + t] = smx[t];
  }
}

// Fused screen + recheck + active + prefill. Sync-free tile loop; each wave fully
// owns its 16 points (screen candidates processed in-wave, no global lists).
__global__ __launch_bounds__(256, 3) void k_main(
    const float* __restrict__ q, const float* __restrict__ vfea,
    const int* __restrict__ coords,
    const float* __restrict__ Woff, const float* __restrict__ boff,
    const float* __restrict__ Wattn, const float* __restrict__ battn,
    const float* __restrict__ Wval, const float* __restrict__ bval,
    const float* __restrict__ Wout, const float* __restrict__ bout,
    float* __restrict__ out, int n, int* __restrict__ ws) {
  __shared__ int4 bfr[24 * 64];  // 24 KB B fragments
  __shared__ int smm[6];

  const int t = threadIdx.x;
  const int wave = t >> 6, lane = t & 63;

  // reduce the 64 minmax partials (wave 0), stage B frags (all)
  if (t < 64) {
    int a0 = ws[OFF_MM + t * 6 + 0], a1 = ws[OFF_MM + t * 6 + 1], a2 = ws[OFF_MM + t * 6 + 2];
    int b0 = ws[OFF_MM + t * 6 + 3], b1 = ws[OFF_MM + t * 6 + 4], b2 = ws[OFF_MM + t * 6 + 5];
    for (int off = 32; off > 0; off >>= 1) {
      a0 = min(a0, __shfl_xor(a0, off, 64));
      a1 = min(a1, __shfl_xor(a1, off, 64));
      a2 = min(a2, __shfl_xor(a2, off, 64));
      b0 = max(b0, __shfl_xor(b0, off, 64));
      b1 = max(b1, __shfl_xor(b1, off, 64));
      b2 = max(b2, __shfl_xor(b2, off, 64));
    }
    if (t == 0) { smm[0] = a0; smm[1] = a1; smm[2] = a2; smm[3] = b0; smm[4] = b1; smm[5] = b2; }
  }
  for (int idx = t; idx < 24 * 64; idx += 256)
    bfr[idx] = reinterpret_cast<const int4*>(ws + OFF_B)[idx];
  __syncthreads();

  const int mn0 = smm[0], mn1 = smm[1], mn2 = smm[2];
  const int mx0 = smm[3], mx1 = smm[4], mx2 = smm[5];
  const float rc0 = (float)(mx0 - mn0), rc1 = (float)(mx1 - mn1), rc2 = (float)(mx2 - mn2);
  const float rcs0 = rc0 * 0.5f, rcs1 = rc1 * 0.5f, rcs2 = rc2 * 0.5f;
  const float rv0 = (float)((mx0 - mn0) / VOXC + 1);
  const float rv1 = (float)((mx1 - mn1) / VOXC + 1);

  const int m = lane & 15, quad = lane >> 4;
  const float* bp = reinterpret_cast<const float*>(ws + OFF_BP);
  float binit[6];
#pragma unroll
  for (int u = 0; u < 6; ++u) binit[u] = bp[u * 16 + m];
  const float4 bv4 = reinterpret_cast<const float4*>(bout)[lane & 31];

  // recheck constants (lane covers cols c0=lane, c1=64+(lane&31))
  const int c0 = lane, c1 = 64 + (lane & 31);
  const int d0 = c0 % 3, d1 = c1 % 3;
  const float s0h = 0.5f * (d0 == 0 ? rc0 : (d0 == 1 ? rc1 : rc2));
  const float s1h = 0.5f * (d1 == 0 ? rc0 : (d1 == 1 ? rc1 : rc2));

  const int ntiles = (n + 63) >> 6;
  const int bid = blockIdx.x;

  float4 x[4], y[4];
  auto loadq = [&](int tile, float4* xv, float4* yv) {
    int prow = tile * 64 + wave * 16 + m;
    const float4* qr = reinterpret_cast<const float4*>(q + (size_t)min(prow, n - 1) * DM);
#pragma unroll
    for (int s = 0; s < 4; ++s) {
      xv[s] = qr[s * 8 + quad * 2];
      yv[s] = qr[s * 8 + quad * 2 + 1];
    }
  };

  int tile = bid;
  if (tile < ntiles) loadq(tile, x, y);

  for (; tile < ntiles; tile += MAIN_GRID) {
    const int basew = tile * 64 + wave * 16;

    // pack current A frags (frees x/y), then prefetch next tile's q
    int4 A[4];
#pragma unroll
    for (int s = 0; s < 4; ++s) {
      A[s].x = (int)((__float_as_uint(x[s].y) & 0xffff0000u) | (__float_as_uint(x[s].x) >> 16));
      A[s].y = (int)((__float_as_uint(x[s].w) & 0xffff0000u) | (__float_as_uint(x[s].z) >> 16));
      A[s].z = (int)((__float_as_uint(y[s].y) & 0xffff0000u) | (__float_as_uint(y[s].x) >> 16));
      A[s].w = (int)((__float_as_uint(y[s].w) & 0xffff0000u) | (__float_as_uint(y[s].z) >> 16));
    }
    int nxt = tile + MAIN_GRID;
    if (nxt < ntiles) loadq(nxt, x, y);

    f32x4 acc[6];
#pragma unroll
    for (int u = 0; u < 6; ++u) acc[u] = (f32x4){binit[u], binit[u], binit[u], binit[u]};
#pragma unroll
    for (int s = 0; s < 4; ++s) {
      union { int4 i; bf16x8 h; } Au;
      Au.i = A[s];
#pragma unroll
      for (int u = 0; u < 6; ++u) {
        union { int4 i; bf16x8 h; } B;
        B.i = bfr[(s * 6 + u) * 64 + lane];
        acc[u] = __builtin_amdgcn_mfma_f32_16x16x32_bf16(Au.h, B.h, acc[u], 0, 0, 0);
      }
    }

    // screen ballot: lane(m,quad), point p=quad*4+r, triples {m, 16+m}, dim j at u=2j+g
    unsigned long long b[4];
#pragma unroll
    for (int r = 0; r < 4; ++r) {
      bool any = false;
#pragma unroll
      for (int g = 0; g < 2; ++g) {
        bool ok = true;
#pragma unroll
        for (int j = 0; j < 3; ++j) {
          float off = acc[2 * j + g][r] * (j == 0 ? rcs0 : (j == 1 ? rcs1 : rcs2));
          ok = ok && (off > -1.0f - MARGIN) && (off < 8.0f + MARGIN);
        }
        any = any || ok;
      }
      b[r] = __ballot(any);
    }
    bool cand = false;
    if (lane < 16) {
      unsigned long long bb = (lane & 1) ? ((lane & 2) ? b[3] : b[1])
                                         : ((lane & 2) ? b[2] : b[0]);
      cand = (basew + lane < n) && (((bb >> ((lane >> 2) * 16)) & 0xffffull) != 0ull);
    }
    unsigned cm = (unsigned)__ballot(cand) & 0xffffu;  // wave-uniform
    unsigned wmask = 0;                                // rows written by active path

    while (cm) {
      int p = __ffs(cm) - 1;
      cm &= cm - 1;
      int pt = basew + p;
      const float* qrow = q + (size_t)pt * DM;

      // exact fp32 recheck (fma order identical to verified path)
      float a0 = boff[c0], a1 = boff[c1];
      for (int k = 0; k < DM; ++k) {
        float qk = qrow[k];
        a0 = fmaf(qk, Woff[k * NCOL + c0], a0);
        a1 = fmaf(qk, Woff[k * NCOL + c1], a1);
      }
      int o0 = (int)(a0 * s0h), o1 = (int)(a1 * s1h);
      unsigned long long m0 = __ballot(o0 >= 0 && o0 < VOXC);
      unsigned long long m1 = __ballot(o1 >= 0 && o1 < VOXC);
      bool mt = false;
      if (lane < 32) {
        int cA = 3 * lane;
        bool bA = (cA < 64) ? ((m0 >> cA) & 1) : ((m1 >> (cA - 64)) & 1);
        bool bB = (cA + 1 < 64) ? ((m0 >> (cA + 1)) & 1) : ((m1 >> (cA - 63)) & 1);
        bool bC = (cA + 2 < 64) ? ((m0 >> (cA + 2)) & 1) : ((m1 >> (cA - 62)) & 1);
        mt = bA && bB && bC;
      }
      unsigned bits = (unsigned)__ballot(mt);
      if (!bits) continue;
      wmask |= 1u << p;

      // ---- active compute (identical math to verified rounds) ----
      float i0 = (float)(coords[pt * 3 + 0] - mn0) * 0.125f;
      float i1 = (float)(coords[pt * 3 + 1] - mn1) * 0.125f;
      float i2 = (float)(coords[pt * 3 + 2] - mn2) * 0.125f;
      float flat = i0 * rv1 * rv0 + i1 * rv0 + i2;
      int g = (int)floorf(flat);
      g = min(max(g, 0), n - 1);

      float w_h = 0.0f;
      if (lane < NATT) {
        float accA = battn[lane];
        for (int k = 0; k < DM; ++k) accA = fmaf(qrow[k], Wattn[k * NATT + lane], accA);
        float mxv = accA;
        mxv = fmaxf(mxv, __shfl_xor(mxv, 1, 4));
        mxv = fmaxf(mxv, __shfl_xor(mxv, 2, 4));
        float e = expf(accA - mxv);
        float s = e;
        s += __shfl_xor(s, 1, 4);
        s += __shfl_xor(s, 2, 4);
        float a = e / s;
        float am = ((bits >> lane) & 1u) ? a : 0.0f;
        float w = am;
        w += __shfl_xor(w, 1, 4);
        w += __shfl_xor(w, 2, 4);
        w_h = w;
      }

      const float* vrow = vfea + (size_t)g * DM;
      float v0 = bval[lane], v1 = bval[lane + 64];
      for (int k = 0; k < DM; ++k) {
        float f = vrow[k];
        v0 = fmaf(f, Wval[k * DM + lane], v0);
        v1 = fmaf(f, Wval[k * DM + lane + 64], v1);
      }
      float wh0 = __shfl(w_h, (lane >> 4) * 4, 64);
      float wh1 = __shfl(w_h, ((lane >> 4) + 4) * 4, 64);
      float o0f = wh0 * v0;
      float o1f = wh1 * v1;

      float s0 = bout[lane], s1 = bout[lane + 64];
      for (int d = 0; d < 64; ++d) {
        float od = __shfl(o0f, d, 64);
        s0 = fmaf(od, Wout[d * DM + lane], s0);
        s1 = fmaf(od, Wout[d * DM + lane + 64], s1);
      }
      for (int d = 0; d < 64; ++d) {
        float od = __shfl(o1f, d, 64);
        s0 = fmaf(od, Wout[(d + 64) * DM + lane], s0);
        s1 = fmaf(od, Wout[(d + 64) * DM + lane + 64], s1);
      }
      out[(size_t)pt * DM + lane] = s0;
      out[(size_t)pt * DM + lane + 64] = s1;
    }

    // b_out prefill for this wave's 16 rows, skipping active-written ones
#pragma unroll
    for (int i = 0; i < 8; ++i) {
      int idx = lane + 64 * i;
      int row = idx >> 5;
      int grow = basew + row;
      if (grow < n && !((wmask >> row) & 1u))
        reinterpret_cast<float4*>(out)[(size_t)grow * 32 + (idx & 31)] = bv4;
    }
  }
}

extern "C" void kernel_launch(void* const* d_in, const int* in_sizes, int n_in,
                              void* d_out, int out_size, void* d_ws, size_t ws_size,
                              hipStream_t stream) {
  const float* q     = (const float*)d_in[0];
  const float* vfea  = (const float*)d_in[1];
  const int*   coords= (const int*)d_in[2];
  const float* Woff  = (const float*)d_in[3];
  const float* boff  = (const float*)d_in[4];
  const float* Wattn = (const float*)d_in[5];
  const float* battn = (const float*)d_in[6];
  const float* Wval  = (const float*)d_in[7];
  const float* bval  = (const float*)d_in[8];
  const float* Wout  = (const float*)d_in[9];
  const float* bout  = (const float*)d_in[10];
  float* out = (float*)d_out;
  int n = in_sizes[0] / DM;
  int* ws = (int*)d_ws;

  k_prep<<<PREP_GRID, 256, 0, stream>>>(coords, Woff, boff, n, ws);
  k_main<<<MAIN_GRID, 256, 0, stream>>>(q, vfea, coords, Woff, boff, Wattn, battn,
                                        Wval, bval, Wout, bout, out, n, ws);
}